// Round 8
// baseline (772.607 us; speedup 1.0000x reference)
//
#include <hip/hip_runtime.h>
#include <hip/hip_bf16.h>

// Problem dims (fixed)
#define NA   128   // agents
#define NN_  16    // neighbors
#define SS   64    // timesteps
#define DD   128   // model dim
#define HH   4     // heads

typedef __attribute__((ext_vector_type(8))) short bf16x8;   // 8 bf16 = 4 VGPRs
typedef __attribute__((ext_vector_type(4))) float floatx4;  // MFMA C/D
typedef __attribute__((ext_vector_type(4))) short shortx4;  // 4 bf16 = 8B

#define MFMA16(a, b, c) __builtin_amdgcn_mfma_f32_16x16x32_bf16((a), (b), (c), 0, 0, 0)

__device__ __forceinline__ short F2BS(float f) {
    __hip_bfloat16 h = __float2bfloat16(f);
    short s;
    __builtin_memcpy(&s, &h, 2);
    return s;
}

// XOR-swizzle for bf16 LDS tiles whose row stride is a multiple of 128B:
// flips byte bits 4..6 by (row&7) -> spreads the 16B slots of a column
// across 8 bank groups. Preserves 8B/16B alignment (bits 0..3 untouched).
// MUST be applied on both write and read sides (ld = row stride in shorts).
__device__ __forceinline__ int swz(int row, int col, int ld) {
    const int byte = ((row * ld + col) << 1) ^ ((row & 7) << 4);
    return byte >> 1;
}

// ---------------------------------------------------------------------------
// Weight prep: bf16 + transpose so MFMA B-fragments (B[k][n], lane n=lane&15,
// k=quad*8+j) are 16B-contiguous reads: store W^T[n][k] row-major.
//   WqT/WkT/WvT/WfcT [128][128], W1iT/W1sT [512][128], W2iT/W2sT/WSIT [128][512]
// ---------------------------------------------------------------------------
__global__ __launch_bounds__(256) void k_prep(
    const float* __restrict__ Wq, const float* __restrict__ Wk,
    const float* __restrict__ Wv,
    const float* __restrict__ Wfc, const float* __restrict__ W1i,
    const float* __restrict__ W2i, const float* __restrict__ WSI,
    const float* __restrict__ W1s, const float* __restrict__ W2s,
    short* __restrict__ WqT, short* __restrict__ WkT, short* __restrict__ WvT,
    short* __restrict__ WfcT, short* __restrict__ W1iT, short* __restrict__ W2iT,
    short* __restrict__ WSIT, short* __restrict__ W1sT, short* __restrict__ W2sT)
{
    const int i = blockIdx.x * 256 + threadIdx.x;   // [0, 65536)
    if (i < 128 * 128) {
        const int n = i >> 7, k = i & 127;
        const int src = k * 128 + n;
        WqT[i]  = F2BS(Wq[src]);
        WkT[i]  = F2BS(Wk[src]);
        WvT[i]  = F2BS(Wv[src]);
        WfcT[i] = F2BS(Wfc[src]);
    }
    {   // [512][128] from (128,512)
        const int n = i >> 7, k = i & 127;
        W1iT[i] = F2BS(W1i[k * 512 + n]);
        W1sT[i] = F2BS(W1s[k * 512 + n]);
    }
    {   // [128][512] from (512,128)
        const int n = i >> 9, f = i & 511;
        W2iT[i] = F2BS(W2i[f * 128 + n]);
        W2sT[i] = F2BS(W2s[f * 128 + n]);
        WSIT[i] = F2BS(WSI[f * 128 + n]);
    }
}

// ---------------------------------------------------------------------------
// Kernel 1 (R7, MFMA, VALIDATED): one block per bn (2048 blocks, 4 waves),
// heads fused. QKV MFMA, masked wave-parallel softmax, att_sum atomics,
// PV MFMA -> res_ws (fp32, aliases out_nb). All LDS tiles XOR-swizzled.
// ---------------------------------------------------------------------------
__global__ __launch_bounds__(256) void k_attn(
    const float* __restrict__ nbr,            // (2048,64,128) fp32
    const int* __restrict__ mask,             // (2048,64,64) int32 0/1
    const short* __restrict__ WqT,            // [128][128] bf16 (W^T)
    const short* __restrict__ WkT,
    const short* __restrict__ WvT,
    float* __restrict__ att_sum,              // (128,4,64,64) fp32, pre-zeroed
    float* __restrict__ res_ws)               // (2048,64,128) fp32
{
    const int bn  = blockIdx.x;
    const int b   = bn >> 4;
    const int tid = threadIdx.x;
    const int lane = tid & 63, quad = lane >> 4, l16 = lane & 15;
    const int m0 = (tid >> 6) * 16;           // wave-private 16 rows

    __shared__ short shE[64 * 128];           // 16 KB; reused as shP after QKV
    __shared__ short shQ[64 * 128];           // 16 KB
    __shared__ short shK[64 * 128];           // 16 KB
    __shared__ short shVT[128 * 64];          // 16 KB, V^T[d][t]
    short* const shP = shE;                   // [64][64] P (wave-private rows)

    // ---- stage E -> bf16 (swizzled), float4 loads ----
    const float* E = nbr + (size_t)bn * 8192;
    for (int i = tid; i < 2048; i += 256) {
        const floatx4 v = *(const floatx4*)&E[i * 4];
        const int row = i >> 5, col = (i & 31) * 4;
        shortx4 o;
#pragma unroll
        for (int j = 0; j < 4; ++j) o[j] = F2BS(v[j]);
        *(shortx4*)&shE[swz(row, col, 128)] = o;
    }

    // mask into regs once, reused by all 4 heads (C-fragment positions)
    const int* mrow = mask + (size_t)bn * 4096;
    int mv[4][4];
#pragma unroll
    for (int nt = 0; nt < 4; ++nt)
#pragma unroll
        for (int r = 0; r < 4; ++r)
            mv[nt][r] = mrow[(m0 + quad * 4 + r) * 64 + nt * 16 + l16];

    __syncthreads();

    // ---- QKV: (64x128)@(128x128) x3, fused over nt ----
    bf16x8 ax[4];
#pragma unroll
    for (int kt = 0; kt < 4; ++kt)
        ax[kt] = *(const bf16x8*)&shE[swz(m0 + l16, kt * 32 + quad * 8, 128)];

#pragma unroll
    for (int nt = 0; nt < 8; ++nt) {
        floatx4 aq = {0.f, 0.f, 0.f, 0.f};
        floatx4 ak = {0.f, 0.f, 0.f, 0.f};
        floatx4 av = {0.f, 0.f, 0.f, 0.f};
#pragma unroll
        for (int kt = 0; kt < 4; ++kt) {
            const size_t wo = (size_t)(nt * 16 + l16) * 128 + kt * 32 + quad * 8;
            aq = MFMA16(ax[kt], *(const bf16x8*)&WqT[wo], aq);
            ak = MFMA16(ax[kt], *(const bf16x8*)&WkT[wo], ak);
            av = MFMA16(ax[kt], *(const bf16x8*)&WvT[wo], av);
        }
        shortx4 ov;
#pragma unroll
        for (int r = 0; r < 4; ++r) {
            const int row = m0 + quad * 4 + r, col = nt * 16 + l16;
            shQ[swz(row, col, 128)] = F2BS(aq[r]);
            shK[swz(row, col, 128)] = F2BS(ak[r]);
            ov[r] = F2BS(av[r]);
        }
        // V stored transposed: VT[d][t], 4 consecutive t per lane -> b64 write
        *(shortx4*)&shVT[swz(nt * 16 + l16, m0 + quad * 4, 64)] = ov;
    }
    __syncthreads();   // shE dead; shQ/shK/shVT visible to all waves

    const float iscale = 0.17677669529663687f; // 1/sqrt(32)
    float* const out = res_ws + (size_t)bn * 8192;

    for (int h = 0; h < 4; ++h) {
        // ---- scores: S = Q_h(64x32) @ K_h^T(32x64) ----
        const bf16x8 qa = *(const bf16x8*)&shQ[swz(m0 + l16, h * 32 + quad * 8, 128)];
        floatx4 sa[4];
#pragma unroll
        for (int nt = 0; nt < 4; ++nt) {
            const bf16x8 kb = *(const bf16x8*)&shK[swz(nt * 16 + l16, h * 32 + quad * 8, 128)];
            const floatx4 z = {0.f, 0.f, 0.f, 0.f};
            sa[nt] = MFMA16(qa, kb, z);
        }
        // ---- masked softmax, wave-parallel (row = 4 nt frags x 16 lanes) ----
        float p[4][4];
#pragma unroll
        for (int r = 0; r < 4; ++r) {
            float m = -1e30f;
#pragma unroll
            for (int nt = 0; nt < 4; ++nt) {
                p[nt][r] = mv[nt][r] ? sa[nt][r] * iscale : -1e9f;
                m = fmaxf(m, p[nt][r]);
            }
            m = fmaxf(m, __shfl_xor(m, 1, 64));
            m = fmaxf(m, __shfl_xor(m, 2, 64));
            m = fmaxf(m, __shfl_xor(m, 4, 64));
            m = fmaxf(m, __shfl_xor(m, 8, 64));
            float sum = 0.f;
#pragma unroll
            for (int nt = 0; nt < 4; ++nt) {
                const float e = __expf(p[nt][r] - m);
                p[nt][r] = e; sum += e;
            }
            sum += __shfl_xor(sum, 1, 64);
            sum += __shfl_xor(sum, 2, 64);
            sum += __shfl_xor(sum, 4, 64);
            sum += __shfl_xor(sum, 8, 64);
            const float inv = 1.f / sum;
#pragma unroll
            for (int nt = 0; nt < 4; ++nt) p[nt][r] *= inv;
        }
        // ---- att_sum atomics + P -> LDS bf16 (own rows) ----
        float* const as = att_sum + ((size_t)(b * 4 + h)) * 4096;
#pragma unroll
        for (int nt = 0; nt < 4; ++nt)
#pragma unroll
            for (int r = 0; r < 4; ++r) {
                const int row = m0 + quad * 4 + r, col = nt * 16 + l16;
                atomicAdd(as + row * 64 + col, p[nt][r]);
                shP[swz(row, col, 64)] = F2BS(p[nt][r]);
            }
        // ---- PV: (64x64)@(64x32) ----
        const bf16x8 pa0 = *(const bf16x8*)&shP[swz(m0 + l16, quad * 8, 64)];
        const bf16x8 pa1 = *(const bf16x8*)&shP[swz(m0 + l16, 32 + quad * 8, 64)];
#pragma unroll
        for (int nt = 0; nt < 2; ++nt) {
            floatx4 acc = {0.f, 0.f, 0.f, 0.f};
            acc = MFMA16(pa0, *(const bf16x8*)&shVT[swz(h * 32 + nt * 16 + l16, quad * 8, 64)], acc);
            acc = MFMA16(pa1, *(const bf16x8*)&shVT[swz(h * 32 + nt * 16 + l16, 32 + quad * 8, 64)], acc);
#pragma unroll
            for (int r = 0; r < 4; ++r)
                out[(m0 + quad * 4 + r) * 128 + h * 32 + nt * 16 + l16] = acc[r];
        }
    }
}

// ---------------------------------------------------------------------------
// MFMA FFN + LN (R11: residual lives in accO itself -> no Xr copy, ~32 fewer
// VGPRs). On entry accO holds X (post-LN residual) and shA holds bf16 X.
// DFF in 4 chunks of 128 -> shH [64][128] = 16 KB.
// out = LN(relu(X@W1)@W2 + X)*g + b, M=64 (16 rows/wave).
// Wave-private rows -> NO barriers inside.
// ---------------------------------------------------------------------------
__device__ __forceinline__ void ffn_mfma(
    const short* shA, short* shH, floatx4 (&accO)[8],
    const short* __restrict__ W1T,   // [512][128] bf16
    const short* __restrict__ W2T,   // [128][512] bf16
    const float* __restrict__ g, const float* __restrict__ bb,
    float* outp, int m0, int lane)
{
    const int quad = lane >> 4, l16 = lane & 15;

    bf16x8 ax[4];
#pragma unroll
    for (int kt = 0; kt < 4; ++kt)
        ax[kt] = *(const bf16x8*)&shA[swz(m0 + l16, kt * 32 + quad * 8, 128)];

#pragma unroll
    for (int fc = 0; fc < 4; ++fc) {
        // H-chunk = relu(X @ W1[:, fc*128 : fc*128+128])
#pragma unroll
        for (int nt = 0; nt < 8; ++nt) {
            floatx4 acc = {0.f, 0.f, 0.f, 0.f};
            const int n0 = fc * 128 + nt * 16;
#pragma unroll
            for (int kt = 0; kt < 4; ++kt) {
                bf16x8 bf = *(const bf16x8*)&W1T[(size_t)(n0 + l16) * 128 + kt * 32 + quad * 8];
                acc = MFMA16(ax[kt], bf, acc);
            }
#pragma unroll
            for (int r = 0; r < 4; ++r)
                shH[swz(m0 + quad * 4 + r, nt * 16 + l16, 128)] = F2BS(fmaxf(acc[r], 0.f));
        }
        // O += H-chunk @ W2[fc*128 : fc*128+128, :]  (in-wave LDS order: safe)
        bf16x8 ah[4];
#pragma unroll
        for (int kt = 0; kt < 4; ++kt)
            ah[kt] = *(const bf16x8*)&shH[swz(m0 + l16, kt * 32 + quad * 8, 128)];
#pragma unroll
        for (int nt = 0; nt < 8; ++nt)
#pragma unroll
            for (int kt = 0; kt < 4; ++kt) {
                bf16x8 bf = *(const bf16x8*)&W2T[(size_t)(nt * 16 + l16) * 512 + fc * 128 + kt * 32 + quad * 8];
                accO[nt] = MFMA16(ah[kt], bf, accO[nt]);
            }
    }

    // LayerNorm: row = m0 + quad*4 + r; 128 cols = 8 frags x 16 quad-lanes
    float mean[4], rstd[4];
#pragma unroll
    for (int r = 0; r < 4; ++r) {
        float p = 0.f;
#pragma unroll
        for (int nt = 0; nt < 8; ++nt) p += accO[nt][r];
        p += __shfl_xor(p, 1, 64); p += __shfl_xor(p, 2, 64);
        p += __shfl_xor(p, 4, 64); p += __shfl_xor(p, 8, 64);
        mean[r] = p * (1.f / 128.f);
        float q = 0.f;
#pragma unroll
        for (int nt = 0; nt < 8; ++nt) { const float d = accO[nt][r] - mean[r]; q += d * d; }
        q += __shfl_xor(q, 1, 64); q += __shfl_xor(q, 2, 64);
        q += __shfl_xor(q, 4, 64); q += __shfl_xor(q, 8, 64);
        rstd[r] = rsqrtf(q * (1.f / 128.f) + 1e-5f);
    }
#pragma unroll
    for (int nt = 0; nt < 8; ++nt) {
        const int colc = nt * 16 + l16;
        const float gc = g[colc], bc = bb[colc];
#pragma unroll
        for (int r = 0; r < 4; ++r) {
            const int row = m0 + quad * 4 + r;
            outp[row * 128 + colc] = (accO[nt][r] - mean[r]) * rstd[r] * gc + bc;
        }
    }
}

// ---------------------------------------------------------------------------
// Kernel 2 (R11): per bn. O = res@Wfc + E; LN in place -> X; FFN+LN -> nb.
// LDS 32 KB (shA 16K + shH 16K); launch_bounds(256,2) so the compiler keeps
// its natural ~90-112 VGPRs (NO spills; R10's (256,4) cap at 64 VGPR caused
// +41 MB/dispatch of scratch traffic). Occupancy: LDS allows 5 blocks/CU,
// VGPR<=128 allows 4 waves/SIMD -> ~46%.
// res_in aliases out_nb (block reads own slice before writing).
// ---------------------------------------------------------------------------
__global__ __launch_bounds__(256, 2) void k_mha_ffn(
    const float* __restrict__ nbr,
    const float* res_in,                      // aliases out_nb
    const short* __restrict__ WfcT,           // [128][128] bf16
    const float* __restrict__ g1, const float* __restrict__ b1,
    const short* __restrict__ W1T, const short* __restrict__ W2T,
    const float* __restrict__ g2, const float* __restrict__ b2,
    float* out_nb)
{
    const int bn = blockIdx.x, tid = threadIdx.x;
    const int w = tid >> 6, lane = tid & 63, quad = lane >> 4, l16 = lane & 15;
    const int m0 = w * 16;
    __shared__ short shA[64 * 128];  // 16 KB
    __shared__ short shH[64 * 128];  // 16 KB

    // stage own 16 rows of res as bf16 (swizzled), float4 loads
    const float* rp = res_in + (size_t)bn * 8192;
    for (int j = lane; j < 512; j += 64) {          // 512 float4 = 2048 elems
        const int row = m0 + (j >> 5), col = (j & 31) * 4;
        const floatx4 v = *(const floatx4*)&rp[row * 128 + col];
        shortx4 o;
#pragma unroll
        for (int t = 0; t < 4; ++t) o[t] = F2BS(v[t]);
        *(shortx4*)&shA[swz(row, col, 128)] = o;
    }

    bf16x8 ax[4];
#pragma unroll
    for (int kt = 0; kt < 4; ++kt)
        ax[kt] = *(const bf16x8*)&shA[swz(m0 + l16, kt * 32 + quad * 8, 128)];

    // O = res @ Wfc + E
    floatx4 acc1[8];
    const float* Eb = nbr + (size_t)bn * 8192;
#pragma unroll
    for (int nt = 0; nt < 8; ++nt)
#pragma unroll
        for (int r = 0; r < 4; ++r)
            acc1[nt][r] = Eb[(m0 + quad * 4 + r) * 128 + nt * 16 + l16];
#pragma unroll
    for (int nt = 0; nt < 8; ++nt)
#pragma unroll
        for (int kt = 0; kt < 4; ++kt) {
            bf16x8 bf = *(const bf16x8*)&WfcT[(size_t)(nt * 16 + l16) * 128 + kt * 32 + quad * 8];
            acc1[nt] = MFMA16(ax[kt], bf, acc1[nt]);
        }

    // LN in place -> acc1 = X (fp32 residual) + bf16 copy into shA (own rows)
    float mean[4], rstd[4];
#pragma unroll
    for (int r = 0; r < 4; ++r) {
        float p = 0.f;
#pragma unroll
        for (int nt = 0; nt < 8; ++nt) p += acc1[nt][r];
        p += __shfl_xor(p, 1, 64); p += __shfl_xor(p, 2, 64);
        p += __shfl_xor(p, 4, 64); p += __shfl_xor(p, 8, 64);
        mean[r] = p * (1.f / 128.f);
        float q = 0.f;
#pragma unroll
        for (int nt = 0; nt < 8; ++nt) { const float d = acc1[nt][r] - mean[r]; q += d * d; }
        q += __shfl_xor(q, 1, 64); q += __shfl_xor(q, 2, 64);
        q += __shfl_xor(q, 4, 64); q += __shfl_xor(q, 8, 64);
        rstd[r] = rsqrtf(q * (1.f / 128.f) + 1e-5f);
    }
#pragma unroll
    for (int nt = 0; nt < 8; ++nt) {
        const int colc = nt * 16 + l16;
        const float gc = g1[colc], bc = b1[colc];
#pragma unroll
        for (int r = 0; r < 4; ++r) {
            acc1[nt][r] = (acc1[nt][r] - mean[r]) * rstd[r] * gc + bc;
            shA[swz(m0 + quad * 4 + r, colc, 128)] = F2BS(acc1[nt][r]);
        }
    }

    ffn_mfma(shA, shH, acc1, W1T, W2T, g2, b2, out_nb + (size_t)bn * 8192, m0, lane);
}

// ---------------------------------------------------------------------------
// Kernel 3a (unchanged): self-softmax + att_factor/16*att_sum; @ x_emb.
// ---------------------------------------------------------------------------
__global__ __launch_bounds__(256) void k_self(
    const float* __restrict__ xemb,            // (128,64,128) fp32
    const float* __restrict__ att_sum,         // (128,4,64,64)
    const float* __restrict__ attf,            // scalar fp32
    float* __restrict__ res_si)                // (128,4,64,128) fp32
{
    const int bh = blockIdx.x;   // b*4 + h
    const int b = bh >> 2;
    const int tid = threadIdx.x;
    __shared__ float xe[64 * 129];
    __shared__ float A[64 * 65];

    const float* xp = xemb + (size_t)b * 8192;
    for (int i = tid; i < 8192; i += 256) xe[(i >> 7) * 129 + (i & 127)] = xp[i];
    __syncthreads();

    const float isc = 0.08838834764831845f; // 1/sqrt(128)
    for (int i = tid; i < 4096; i += 256) {
        const int s = i >> 6, t = i & 63;
        const float* xs = xe + s * 129;
        const float* xt = xe + t * 129;
        float a0 = 0.f, a1 = 0.f, a2 = 0.f, a3 = 0.f;
#pragma unroll
        for (int d = 0; d < 128; d += 4) {
            a0 += xs[d]     * xt[d];
            a1 += xs[d + 1] * xt[d + 1];
            a2 += xs[d + 2] * xt[d + 2];
            a3 += xs[d + 3] * xt[d + 3];
        }
        A[s * 65 + t] = ((a0 + a1) + (a2 + a3)) * isc;
    }
    __syncthreads();
    if (tid < 64) {
        float* r = A + tid * 65;
        float m = r[0];
        for (int t = 1; t < 64; ++t) m = fmaxf(m, r[t]);
        float sum = 0.f;
        for (int t = 0; t < 64; ++t) { const float e = __expf(r[t] - m); r[t] = e; sum += e; }
        const float inv = 1.f / sum;
        for (int t = 0; t < 64; ++t) r[t] *= inv;
    }
    __syncthreads();
    const float f = attf[0] * (1.f / 16.f);
    const float* as = att_sum + (size_t)bh * 4096;
    for (int i = tid; i < 4096; i += 256)
        A[(i >> 6) * 65 + (i & 63)] += f * as[i];
    __syncthreads();

    float* op = res_si + (size_t)bh * 8192;
    for (int i = tid; i < 8192; i += 256) {
        const int s = i >> 7, d = i & 127;
        const float* ar = A + s * 65;
        float a0 = 0.f, a1 = 0.f;
#pragma unroll
        for (int t = 0; t < 64; t += 2) {
            a0 += ar[t]     * xe[t * 129 + d];
            a1 += ar[t + 1] * xe[(t + 1) * 129 + d];
        }
        op[i] = a0 + a1;
    }
}

// ---------------------------------------------------------------------------
// Kernel 3b (VALIDATED in R8; Xr-free ffn): per b. X1 = cat_h(res_si)@W_SI
// (K=512); FFN+LN -> x. shC [64][512] bf16 (swz512); after one barrier
// re-split into shA[64][128] + shH[64][128] (both swz128).
// ---------------------------------------------------------------------------
__global__ __launch_bounds__(256, 2) void k_si_ffn(
    const float* __restrict__ res_si,
    const short* __restrict__ WSIT,            // [128][512] bf16
    const short* __restrict__ W1T, const short* __restrict__ W2T,
    const float* __restrict__ g, const float* __restrict__ bb,
    float* __restrict__ out_x)
{
    const int b = blockIdx.x, tid = threadIdx.x;
    const int w = tid >> 6, lane = tid & 63, quad = lane >> 4, l16 = lane & 15;
    const int m0 = w * 16;
    __shared__ short shC[64 * 512];            // 64 KB
    short* shA = shC;                          // [64][128] after barrier
    short* shH = shC + 64 * 128;               // [64][128] after barrier

    // stage own 16 rows of cat_h(res_si) as bf16: row s, k = h*128+d (swz512)
    const float* rs = res_si + (size_t)b * 4 * 8192;
    for (int i = lane; i < 8192; i += 64) {
        const int row = m0 + (i >> 9), k = i & 511;
        const int h = k >> 7, d = k & 127;
        shC[swz(row, k, 512)] = F2BS(rs[((size_t)h * 64 + row) * 128 + d]);
    }

    // X1 = cat @ W_SI  (M=64,K=512,N=128), no residual/LN
    floatx4 acc1[8];
#pragma unroll
    for (int nt = 0; nt < 8; ++nt) acc1[nt] = (floatx4){0.f, 0.f, 0.f, 0.f};
    for (int kt = 0; kt < 16; ++kt) {
        bf16x8 a = *(const bf16x8*)&shC[swz(m0 + l16, kt * 32 + quad * 8, 512)];
#pragma unroll
        for (int nt = 0; nt < 8; ++nt) {
            bf16x8 bf = *(const bf16x8*)&WSIT[(size_t)(nt * 16 + l16) * 512 + kt * 32 + quad * 8];
            acc1[nt] = MFMA16(a, bf, acc1[nt]);
        }
    }

    __syncthreads();   // all step-A reads of shC done before overlay writes

#pragma unroll
    for (int nt = 0; nt < 8; ++nt)
#pragma unroll
        for (int r = 0; r < 4; ++r)
            shA[swz(m0 + quad * 4 + r, nt * 16 + l16, 128)] = F2BS(acc1[nt][r]);

    ffn_mfma(shA, shH, acc1, W1T, W2T, g, bb, out_x + (size_t)b * 8192, m0, lane);
}

// ---------------------------------------------------------------------------
extern "C" void kernel_launch(void* const* d_in, const int* in_sizes, int n_in,
                              void* d_out, int out_size, void* d_ws, size_t ws_size,
                              hipStream_t stream) {
    const float* x_emb = (const float*)d_in[0];
    const float* nbr   = (const float*)d_in[1];
    const int*   mask  = (const int*)d_in[2];
    const float* attf  = (const float*)d_in[3];
    const float* Wq    = (const float*)d_in[4];
    const float* Wk    = (const float*)d_in[5];
    const float* Wv    = (const float*)d_in[6];
    const float* Wfc   = (const float*)d_in[7];
    const float* g_mha = (const float*)d_in[8];
    const float* b_mha = (const float*)d_in[9];
    const float* WSI   = (const float*)d_in[10];
    const float* W1s   = (const float*)d_in[11];
    const float* W2s   = (const float*)d_in[12];
    const float* gs    = (const float*)d_in[13];
    const float* bs    = (const float*)d_in[14];
    const float* W1i   = (const float*)d_in[15];
    const float* W2i   = (const float*)d_in[16];
    const float* gi    = (const float*)d_in[17];
    const float* bi    = (const float*)d_in[18];

    // workspace (~27 MB):
    //   [0, 8M)            att_sum fp32 (zeroed each call)
    //   [8M+256, ~24.8M)   res_si fp32 (128*4*64*128)
    //   [25M, +96K)        bf16 W^T for QKV
    //   [26M, +656K)       bf16 transposed weights (FFN/SI)
    float* att_sum = (float*)d_ws;
    float* res_si = (float*)((char*)d_ws + (size_t)8 * 1024 * 1024 + 256);
    short* wqkv = (short*)((char*)d_ws + (size_t)25 * 1024 * 1024);
    short* WqT  = wqkv;                // 16384
    short* WkT  = WqT + 16384;
    short* WvT  = WkT + 16384;
    short* wb   = (short*)((char*)d_ws + (size_t)26 * 1024 * 1024);
    short* WfcT = wb;                  // 16384
    short* W1iT = WfcT + 16384;        // 65536
    short* W2iT = W1iT + 65536;
    short* WSIT = W2iT + 65536;
    short* W1sT = WSIT + 65536;
    short* W2sT = W1sT + 65536;

    float* out_x  = (float*)d_out;                       // output 0: x
    float* out_nb = out_x + (size_t)NA * SS * DD;        // output 1: nb
    float* res_ws = out_nb;   // res staged in out_nb storage (element-exact)

    hipMemsetAsync(d_ws, 0, (size_t)NA * HH * SS * SS * sizeof(float), stream);

    k_prep<<<256, 256, 0, stream>>>(Wq, Wk, Wv, Wfc, W1i, W2i, WSI, W1s, W2s,
                                    WqT, WkT, WvT,
                                    WfcT, W1iT, W2iT, WSIT, W1sT, W2sT);
    k_attn<<<NA * NN_, 256, 0, stream>>>(nbr, mask, WqT, WkT, WvT,
                                         att_sum, res_ws);
    k_mha_ffn<<<NA * NN_, 256, 0, stream>>>(nbr, res_ws, WfcT, g_mha, b_mha,
                                            W1iT, W2iT, gi, bi, out_nb);
    k_self<<<NA * HH, 256, 0, stream>>>(x_emb, att_sum, attf, res_si);
    k_si_ffn<<<NA, 256, 0, stream>>>(res_si, WSIT, W1sT, W2sT, gs, bs, out_x);
}

// Round 9
// 627.850 us; speedup vs baseline: 1.2306x; 1.2306x over previous
//
#include <hip/hip_runtime.h>
#include <hip/hip_bf16.h>

// Problem dims (fixed)
#define NA   128   // agents
#define NN_  16    // neighbors
#define SS   64    // timesteps
#define DD   128   // model dim
#define HH   4     // heads

typedef __attribute__((ext_vector_type(8))) short bf16x8;   // 8 bf16 = 4 VGPRs
typedef __attribute__((ext_vector_type(4))) float floatx4;  // MFMA C/D
typedef __attribute__((ext_vector_type(4))) short shortx4;  // 4 bf16 = 8B

#define MFMA16(a, b, c) __builtin_amdgcn_mfma_f32_16x16x32_bf16((a), (b), (c), 0, 0, 0)

__device__ __forceinline__ short F2BS(float f) {
    __hip_bfloat16 h = __float2bfloat16(f);
    short s;
    __builtin_memcpy(&s, &h, 2);
    return s;
}

// XOR-swizzle for bf16 LDS tiles whose row stride is a multiple of 128B:
// flips byte bits 4..6 by (row&7) -> spreads the 16B slots of a column
// across 8 bank groups. Preserves 8B/16B alignment (bits 0..3 untouched).
// MUST be applied on both write and read sides (ld = row stride in shorts).
__device__ __forceinline__ int swz(int row, int col, int ld) {
    const int byte = ((row * ld + col) << 1) ^ ((row & 7) << 4);
    return byte >> 1;
}

// ---------------------------------------------------------------------------
// Weight prep: bf16 + transpose so MFMA B-fragments (B[k][n], lane n=lane&15,
// k=quad*8+j) are 16B-contiguous reads: store W^T[n][k] row-major.
//   WqT/WkT/WvT/WfcT [128][128], W1iT/W1sT [512][128], W2iT/W2sT/WSIT [128][512]
// ---------------------------------------------------------------------------
__global__ __launch_bounds__(256) void k_prep(
    const float* __restrict__ Wq, const float* __restrict__ Wk,
    const float* __restrict__ Wv,
    const float* __restrict__ Wfc, const float* __restrict__ W1i,
    const float* __restrict__ W2i, const float* __restrict__ WSI,
    const float* __restrict__ W1s, const float* __restrict__ W2s,
    short* __restrict__ WqT, short* __restrict__ WkT, short* __restrict__ WvT,
    short* __restrict__ WfcT, short* __restrict__ W1iT, short* __restrict__ W2iT,
    short* __restrict__ WSIT, short* __restrict__ W1sT, short* __restrict__ W2sT)
{
    const int i = blockIdx.x * 256 + threadIdx.x;   // [0, 65536)
    if (i < 128 * 128) {
        const int n = i >> 7, k = i & 127;
        const int src = k * 128 + n;
        WqT[i]  = F2BS(Wq[src]);
        WkT[i]  = F2BS(Wk[src]);
        WvT[i]  = F2BS(Wv[src]);
        WfcT[i] = F2BS(Wfc[src]);
    }
    {   // [512][128] from (128,512)
        const int n = i >> 7, k = i & 127;
        W1iT[i] = F2BS(W1i[k * 512 + n]);
        W1sT[i] = F2BS(W1s[k * 512 + n]);
    }
    {   // [128][512] from (512,128)
        const int n = i >> 9, f = i & 511;
        W2iT[i] = F2BS(W2i[f * 128 + n]);
        W2sT[i] = F2BS(W2s[f * 128 + n]);
        WSIT[i] = F2BS(WSI[f * 128 + n]);
    }
}

// ---------------------------------------------------------------------------
// Kernel 1 (R7, MFMA, VALIDATED): one block per bn (2048 blocks, 4 waves),
// heads fused. QKV MFMA, masked wave-parallel softmax, att_sum atomics,
// PV MFMA -> res_ws (fp32, aliases out_nb). All LDS tiles XOR-swizzled.
// ---------------------------------------------------------------------------
__global__ __launch_bounds__(256) void k_attn(
    const float* __restrict__ nbr,            // (2048,64,128) fp32
    const int* __restrict__ mask,             // (2048,64,64) int32 0/1
    const short* __restrict__ WqT,            // [128][128] bf16 (W^T)
    const short* __restrict__ WkT,
    const short* __restrict__ WvT,
    float* __restrict__ att_sum,              // (128,4,64,64) fp32, pre-zeroed
    float* __restrict__ res_ws)               // (2048,64,128) fp32
{
    const int bn  = blockIdx.x;
    const int b   = bn >> 4;
    const int tid = threadIdx.x;
    const int lane = tid & 63, quad = lane >> 4, l16 = lane & 15;
    const int m0 = (tid >> 6) * 16;           // wave-private 16 rows

    __shared__ short shE[64 * 128];           // 16 KB; reused as shP after QKV
    __shared__ short shQ[64 * 128];           // 16 KB
    __shared__ short shK[64 * 128];           // 16 KB
    __shared__ short shVT[128 * 64];          // 16 KB, V^T[d][t]
    short* const shP = shE;                   // [64][64] P (wave-private rows)

    // ---- stage E -> bf16 (swizzled), float4 loads ----
    const float* E = nbr + (size_t)bn * 8192;
    for (int i = tid; i < 2048; i += 256) {
        const floatx4 v = *(const floatx4*)&E[i * 4];
        const int row = i >> 5, col = (i & 31) * 4;
        shortx4 o;
#pragma unroll
        for (int j = 0; j < 4; ++j) o[j] = F2BS(v[j]);
        *(shortx4*)&shE[swz(row, col, 128)] = o;
    }

    // mask into regs once, reused by all 4 heads (C-fragment positions)
    const int* mrow = mask + (size_t)bn * 4096;
    int mv[4][4];
#pragma unroll
    for (int nt = 0; nt < 4; ++nt)
#pragma unroll
        for (int r = 0; r < 4; ++r)
            mv[nt][r] = mrow[(m0 + quad * 4 + r) * 64 + nt * 16 + l16];

    __syncthreads();

    // ---- QKV: (64x128)@(128x128) x3, fused over nt ----
    bf16x8 ax[4];
#pragma unroll
    for (int kt = 0; kt < 4; ++kt)
        ax[kt] = *(const bf16x8*)&shE[swz(m0 + l16, kt * 32 + quad * 8, 128)];

#pragma unroll
    for (int nt = 0; nt < 8; ++nt) {
        floatx4 aq = {0.f, 0.f, 0.f, 0.f};
        floatx4 ak = {0.f, 0.f, 0.f, 0.f};
        floatx4 av = {0.f, 0.f, 0.f, 0.f};
#pragma unroll
        for (int kt = 0; kt < 4; ++kt) {
            const size_t wo = (size_t)(nt * 16 + l16) * 128 + kt * 32 + quad * 8;
            aq = MFMA16(ax[kt], *(const bf16x8*)&WqT[wo], aq);
            ak = MFMA16(ax[kt], *(const bf16x8*)&WkT[wo], ak);
            av = MFMA16(ax[kt], *(const bf16x8*)&WvT[wo], av);
        }
        shortx4 ov;
#pragma unroll
        for (int r = 0; r < 4; ++r) {
            const int row = m0 + quad * 4 + r, col = nt * 16 + l16;
            shQ[swz(row, col, 128)] = F2BS(aq[r]);
            shK[swz(row, col, 128)] = F2BS(ak[r]);
            ov[r] = F2BS(av[r]);
        }
        // V stored transposed: VT[d][t], 4 consecutive t per lane -> b64 write
        *(shortx4*)&shVT[swz(nt * 16 + l16, m0 + quad * 4, 64)] = ov;
    }
    __syncthreads();   // shE dead; shQ/shK/shVT visible to all waves

    const float iscale = 0.17677669529663687f; // 1/sqrt(32)
    float* const out = res_ws + (size_t)bn * 8192;

    for (int h = 0; h < 4; ++h) {
        // ---- scores: S = Q_h(64x32) @ K_h^T(32x64) ----
        const bf16x8 qa = *(const bf16x8*)&shQ[swz(m0 + l16, h * 32 + quad * 8, 128)];
        floatx4 sa[4];
#pragma unroll
        for (int nt = 0; nt < 4; ++nt) {
            const bf16x8 kb = *(const bf16x8*)&shK[swz(nt * 16 + l16, h * 32 + quad * 8, 128)];
            const floatx4 z = {0.f, 0.f, 0.f, 0.f};
            sa[nt] = MFMA16(qa, kb, z);
        }
        // ---- masked softmax, wave-parallel (row = 4 nt frags x 16 lanes) ----
        float p[4][4];
#pragma unroll
        for (int r = 0; r < 4; ++r) {
            float m = -1e30f;
#pragma unroll
            for (int nt = 0; nt < 4; ++nt) {
                p[nt][r] = mv[nt][r] ? sa[nt][r] * iscale : -1e9f;
                m = fmaxf(m, p[nt][r]);
            }
            m = fmaxf(m, __shfl_xor(m, 1, 64));
            m = fmaxf(m, __shfl_xor(m, 2, 64));
            m = fmaxf(m, __shfl_xor(m, 4, 64));
            m = fmaxf(m, __shfl_xor(m, 8, 64));
            float sum = 0.f;
#pragma unroll
            for (int nt = 0; nt < 4; ++nt) {
                const float e = __expf(p[nt][r] - m);
                p[nt][r] = e; sum += e;
            }
            sum += __shfl_xor(sum, 1, 64);
            sum += __shfl_xor(sum, 2, 64);
            sum += __shfl_xor(sum, 4, 64);
            sum += __shfl_xor(sum, 8, 64);
            const float inv = 1.f / sum;
#pragma unroll
            for (int nt = 0; nt < 4; ++nt) p[nt][r] *= inv;
        }
        // ---- att_sum atomics + P -> LDS bf16 (own rows) ----
        float* const as = att_sum + ((size_t)(b * 4 + h)) * 4096;
#pragma unroll
        for (int nt = 0; nt < 4; ++nt)
#pragma unroll
            for (int r = 0; r < 4; ++r) {
                const int row = m0 + quad * 4 + r, col = nt * 16 + l16;
                atomicAdd(as + row * 64 + col, p[nt][r]);
                shP[swz(row, col, 64)] = F2BS(p[nt][r]);
            }
        // ---- PV: (64x64)@(64x32) ----
        const bf16x8 pa0 = *(const bf16x8*)&shP[swz(m0 + l16, quad * 8, 64)];
        const bf16x8 pa1 = *(const bf16x8*)&shP[swz(m0 + l16, 32 + quad * 8, 64)];
#pragma unroll
        for (int nt = 0; nt < 2; ++nt) {
            floatx4 acc = {0.f, 0.f, 0.f, 0.f};
            acc = MFMA16(pa0, *(const bf16x8*)&shVT[swz(h * 32 + nt * 16 + l16, quad * 8, 64)], acc);
            acc = MFMA16(pa1, *(const bf16x8*)&shVT[swz(h * 32 + nt * 16 + l16, 32 + quad * 8, 64)], acc);
#pragma unroll
            for (int r = 0; r < 4; ++r)
                out[(m0 + quad * 4 + r) * 128 + h * 32 + nt * 16 + l16] = acc[r];
        }
    }
}

// ---------------------------------------------------------------------------
// MFMA FFN + LN (single-tile helper, used by k_si_ffn; VALIDATED R8/R11).
// On entry accO holds X (post-LN residual) and shA holds bf16 X.
// DFF in 4 chunks of 128 -> shH [64][128] = 16 KB.
// ---------------------------------------------------------------------------
__device__ __forceinline__ void ffn_mfma(
    const short* shA, short* shH, floatx4 (&accO)[8],
    const short* __restrict__ W1T,   // [512][128] bf16
    const short* __restrict__ W2T,   // [128][512] bf16
    const float* __restrict__ g, const float* __restrict__ bb,
    float* outp, int m0, int lane)
{
    const int quad = lane >> 4, l16 = lane & 15;

    bf16x8 ax[4];
#pragma unroll
    for (int kt = 0; kt < 4; ++kt)
        ax[kt] = *(const bf16x8*)&shA[swz(m0 + l16, kt * 32 + quad * 8, 128)];

#pragma unroll
    for (int fc = 0; fc < 4; ++fc) {
#pragma unroll
        for (int nt = 0; nt < 8; ++nt) {
            floatx4 acc = {0.f, 0.f, 0.f, 0.f};
            const int n0 = fc * 128 + nt * 16;
#pragma unroll
            for (int kt = 0; kt < 4; ++kt) {
                bf16x8 bf = *(const bf16x8*)&W1T[(size_t)(n0 + l16) * 128 + kt * 32 + quad * 8];
                acc = MFMA16(ax[kt], bf, acc);
            }
#pragma unroll
            for (int r = 0; r < 4; ++r)
                shH[swz(m0 + quad * 4 + r, nt * 16 + l16, 128)] = F2BS(fmaxf(acc[r], 0.f));
        }
        bf16x8 ah[4];
#pragma unroll
        for (int kt = 0; kt < 4; ++kt)
            ah[kt] = *(const bf16x8*)&shH[swz(m0 + l16, kt * 32 + quad * 8, 128)];
#pragma unroll
        for (int nt = 0; nt < 8; ++nt)
#pragma unroll
            for (int kt = 0; kt < 4; ++kt) {
                bf16x8 bf = *(const bf16x8*)&W2T[(size_t)(nt * 16 + l16) * 512 + fc * 128 + kt * 32 + quad * 8];
                accO[nt] = MFMA16(ah[kt], bf, accO[nt]);
            }
    }

    float mean[4], rstd[4];
#pragma unroll
    for (int r = 0; r < 4; ++r) {
        float p = 0.f;
#pragma unroll
        for (int nt = 0; nt < 8; ++nt) p += accO[nt][r];
        p += __shfl_xor(p, 1, 64); p += __shfl_xor(p, 2, 64);
        p += __shfl_xor(p, 4, 64); p += __shfl_xor(p, 8, 64);
        mean[r] = p * (1.f / 128.f);
        float q = 0.f;
#pragma unroll
        for (int nt = 0; nt < 8; ++nt) { const float d = accO[nt][r] - mean[r]; q += d * d; }
        q += __shfl_xor(q, 1, 64); q += __shfl_xor(q, 2, 64);
        q += __shfl_xor(q, 4, 64); q += __shfl_xor(q, 8, 64);
        rstd[r] = rsqrtf(q * (1.f / 128.f) + 1e-5f);
    }
#pragma unroll
    for (int nt = 0; nt < 8; ++nt) {
        const int colc = nt * 16 + l16;
        const float gc = g[colc], bc = bb[colc];
#pragma unroll
        for (int r = 0; r < 4; ++r) {
            const int row = m0 + quad * 4 + r;
            outp[row * 128 + colc] = (accO[nt][r] - mean[r]) * rstd[r] * gc + bc;
        }
    }
}

// in-place LN over C-fragment regs + bf16 store to swizzled LDS (own rows)
__device__ __forceinline__ void ln_inplace(
    floatx4 (&acc)[8], const float* __restrict__ g, const float* __restrict__ bb,
    short* shX, int m0, int quad, int l16)
{
    float mean[4], rstd[4];
#pragma unroll
    for (int r = 0; r < 4; ++r) {
        float p = 0.f;
#pragma unroll
        for (int nt = 0; nt < 8; ++nt) p += acc[nt][r];
        p += __shfl_xor(p, 1, 64); p += __shfl_xor(p, 2, 64);
        p += __shfl_xor(p, 4, 64); p += __shfl_xor(p, 8, 64);
        mean[r] = p * (1.f / 128.f);
        float q = 0.f;
#pragma unroll
        for (int nt = 0; nt < 8; ++nt) { const float d = acc[nt][r] - mean[r]; q += d * d; }
        q += __shfl_xor(q, 1, 64); q += __shfl_xor(q, 2, 64);
        q += __shfl_xor(q, 4, 64); q += __shfl_xor(q, 8, 64);
        rstd[r] = rsqrtf(q * (1.f / 128.f) + 1e-5f);
    }
#pragma unroll
    for (int nt = 0; nt < 8; ++nt) {
        const int colc = nt * 16 + l16;
        const float gc = g[colc], bc = bb[colc];
#pragma unroll
        for (int r = 0; r < 4; ++r) {
            acc[nt][r] = (acc[nt][r] - mean[r]) * rstd[r] * gc + bc;
            shX[swz(m0 + quad * 4 + r, colc, 128)] = F2BS(acc[nt][r]);
        }
    }
}

// ---------------------------------------------------------------------------
// Kernel 2 (R12): TWO bn tiles per block (grid 1024). Every weight B-fragment
// is loaded ONCE and feeds TWO independent MFMAs (acc0/acc1) -> halves the
// single-use L2 load count that made this kernel latency-bound (R6/R10/R11:
// occupancy 23-46% barely moved dur; MfmaUtil~5%, all pipes idle).
// LDS 32 KB: lds[t] holds res->X, then is overlaid by the H chunk (in-wave,
// wave-private rows, same buffer -> ordering guaranteed; pattern validated in
// R11 k_mha_ffn / R8 k_si_ffn). Static-indexed reg arrays only.
// ---------------------------------------------------------------------------
__global__ __launch_bounds__(256, 2) void k_mha_ffn(
    const float* __restrict__ nbr,
    const float* res_in,                      // aliases out_nb
    const short* __restrict__ WfcT,           // [128][128] bf16
    const float* __restrict__ g1, const float* __restrict__ b1,
    const short* __restrict__ W1T, const short* __restrict__ W2T,
    const float* __restrict__ g2, const float* __restrict__ b2,
    float* out_nb)
{
    const int bn0 = blockIdx.x * 2;
    const int tid = threadIdx.x;
    const int lane = tid & 63, quad = lane >> 4, l16 = lane & 15;
    const int m0 = (tid >> 6) * 16;
    __shared__ short lds0[64 * 128];   // tile0: res -> X -> H chunks (16 KB)
    __shared__ short lds1[64 * 128];   // tile1: same (16 KB)

    // ---- stage both res tiles (own rows, swizzled, float4 loads) ----
    const float* rp0 = res_in + (size_t)bn0 * 8192;
    const float* rp1 = res_in + (size_t)(bn0 + 1) * 8192;
    for (int j = lane; j < 512; j += 64) {
        const int row = m0 + (j >> 5), col = (j & 31) * 4;
        const floatx4 v0 = *(const floatx4*)&rp0[row * 128 + col];
        const floatx4 v1 = *(const floatx4*)&rp1[row * 128 + col];
        shortx4 o0, o1;
#pragma unroll
        for (int t = 0; t < 4; ++t) { o0[t] = F2BS(v0[t]); o1[t] = F2BS(v1[t]); }
        *(shortx4*)&lds0[swz(row, col, 128)] = o0;
        *(shortx4*)&lds1[swz(row, col, 128)] = o1;
    }

    bf16x8 ax0[4], ax1[4];
#pragma unroll
    for (int kt = 0; kt < 4; ++kt) {
        ax0[kt] = *(const bf16x8*)&lds0[swz(m0 + l16, kt * 32 + quad * 8, 128)];
        ax1[kt] = *(const bf16x8*)&lds1[swz(m0 + l16, kt * 32 + quad * 8, 128)];
    }

    // ---- O = res @ Wfc + E, both tiles, shared weight fragments ----
    floatx4 acc0[8], acc1[8];
    const float* E0 = nbr + (size_t)bn0 * 8192;
    const float* E1 = nbr + (size_t)(bn0 + 1) * 8192;
#pragma unroll
    for (int nt = 0; nt < 8; ++nt)
#pragma unroll
        for (int r = 0; r < 4; ++r) {
            const int idx = (m0 + quad * 4 + r) * 128 + nt * 16 + l16;
            acc0[nt][r] = E0[idx];
            acc1[nt][r] = E1[idx];
        }
#pragma unroll
    for (int nt = 0; nt < 8; ++nt)
#pragma unroll
        for (int kt = 0; kt < 4; ++kt) {
            bf16x8 bf = *(const bf16x8*)&WfcT[(size_t)(nt * 16 + l16) * 128 + kt * 32 + quad * 8];
            acc0[nt] = MFMA16(ax0[kt], bf, acc0[nt]);
            acc1[nt] = MFMA16(ax1[kt], bf, acc1[nt]);
        }

    // ---- LN in place -> acc = X; bf16 X into lds (own rows) ----
    ln_inplace(acc0, g1, b1, lds0, m0, quad, l16);
    ln_inplace(acc1, g1, b1, lds1, m0, quad, l16);

    // reload A fragments = X
#pragma unroll
    for (int kt = 0; kt < 4; ++kt) {
        ax0[kt] = *(const bf16x8*)&lds0[swz(m0 + l16, kt * 32 + quad * 8, 128)];
        ax1[kt] = *(const bf16x8*)&lds1[swz(m0 + l16, kt * 32 + quad * 8, 128)];
    }

    // ---- FFN: DFF in 4 chunks; H overlays lds (X already in ax regs) ----
#pragma unroll
    for (int fc = 0; fc < 4; ++fc) {
#pragma unroll
        for (int nt = 0; nt < 8; ++nt) {
            floatx4 h0 = {0.f, 0.f, 0.f, 0.f};
            floatx4 h1 = {0.f, 0.f, 0.f, 0.f};
            const int n0 = fc * 128 + nt * 16;
#pragma unroll
            for (int kt = 0; kt < 4; ++kt) {
                bf16x8 bf = *(const bf16x8*)&W1T[(size_t)(n0 + l16) * 128 + kt * 32 + quad * 8];
                h0 = MFMA16(ax0[kt], bf, h0);
                h1 = MFMA16(ax1[kt], bf, h1);
            }
#pragma unroll
            for (int r = 0; r < 4; ++r) {
                const int o = swz(m0 + quad * 4 + r, nt * 16 + l16, 128);
                lds0[o] = F2BS(fmaxf(h0[r], 0.f));
                lds1[o] = F2BS(fmaxf(h1[r], 0.f));
            }
        }
        bf16x8 ah0[4], ah1[4];
#pragma unroll
        for (int kt = 0; kt < 4; ++kt) {
            ah0[kt] = *(const bf16x8*)&lds0[swz(m0 + l16, kt * 32 + quad * 8, 128)];
            ah1[kt] = *(const bf16x8*)&lds1[swz(m0 + l16, kt * 32 + quad * 8, 128)];
        }
#pragma unroll
        for (int nt = 0; nt < 8; ++nt)
#pragma unroll
            for (int kt = 0; kt < 4; ++kt) {
                bf16x8 bf = *(const bf16x8*)&W2T[(size_t)(nt * 16 + l16) * 512 + fc * 128 + kt * 32 + quad * 8];
                acc0[nt] = MFMA16(ah0[kt], bf, acc0[nt]);
                acc1[nt] = MFMA16(ah1[kt], bf, acc1[nt]);
            }
    }

    // ---- final LN + store (write direct to global; lds holds H garbage) ----
    float* const op0 = out_nb + (size_t)bn0 * 8192;
    float* const op1 = out_nb + (size_t)(bn0 + 1) * 8192;
    {
        float mean[4], rstd[4];
#pragma unroll
        for (int r = 0; r < 4; ++r) {
            float p = 0.f;
#pragma unroll
            for (int nt = 0; nt < 8; ++nt) p += acc0[nt][r];
            p += __shfl_xor(p, 1, 64); p += __shfl_xor(p, 2, 64);
            p += __shfl_xor(p, 4, 64); p += __shfl_xor(p, 8, 64);
            mean[r] = p * (1.f / 128.f);
            float q = 0.f;
#pragma unroll
            for (int nt = 0; nt < 8; ++nt) { const float d = acc0[nt][r] - mean[r]; q += d * d; }
            q += __shfl_xor(q, 1, 64); q += __shfl_xor(q, 2, 64);
            q += __shfl_xor(q, 4, 64); q += __shfl_xor(q, 8, 64);
            rstd[r] = rsqrtf(q * (1.f / 128.f) + 1e-5f);
        }
#pragma unroll
        for (int nt = 0; nt < 8; ++nt) {
            const int colc = nt * 16 + l16;
            const float gc = g2[colc], bc = b2[colc];
#pragma unroll
            for (int r = 0; r < 4; ++r)
                op0[(m0 + quad * 4 + r) * 128 + colc] = (acc0[nt][r] - mean[r]) * rstd[r] * gc + bc;
        }
    }
    {
        float mean[4], rstd[4];
#pragma unroll
        for (int r = 0; r < 4; ++r) {
            float p = 0.f;
#pragma unroll
            for (int nt = 0; nt < 8; ++nt) p += acc1[nt][r];
            p += __shfl_xor(p, 1, 64); p += __shfl_xor(p, 2, 64);
            p += __shfl_xor(p, 4, 64); p += __shfl_xor(p, 8, 64);
            mean[r] = p * (1.f / 128.f);
            float q = 0.f;
#pragma unroll
            for (int nt = 0; nt < 8; ++nt) { const float d = acc1[nt][r] - mean[r]; q += d * d; }
            q += __shfl_xor(q, 1, 64); q += __shfl_xor(q, 2, 64);
            q += __shfl_xor(q, 4, 64); q += __shfl_xor(q, 8, 64);
            rstd[r] = rsqrtf(q * (1.f / 128.f) + 1e-5f);
        }
#pragma unroll
        for (int nt = 0; nt < 8; ++nt) {
            const int colc = nt * 16 + l16;
            const float gc = g2[colc], bc = b2[colc];
#pragma unroll
            for (int r = 0; r < 4; ++r)
                op1[(m0 + quad * 4 + r) * 128 + colc] = (acc1[nt][r] - mean[r]) * rstd[r] * gc + bc;
        }
    }
}

// ---------------------------------------------------------------------------
// Kernel 3a (unchanged): self-softmax + att_factor/16*att_sum; @ x_emb.
// ---------------------------------------------------------------------------
__global__ __launch_bounds__(256) void k_self(
    const float* __restrict__ xemb,            // (128,64,128) fp32
    const float* __restrict__ att_sum,         // (128,4,64,64)
    const float* __restrict__ attf,            // scalar fp32
    float* __restrict__ res_si)                // (128,4,64,128) fp32
{
    const int bh = blockIdx.x;   // b*4 + h
    const int b = bh >> 2;
    const int tid = threadIdx.x;
    __shared__ float xe[64 * 129];
    __shared__ float A[64 * 65];

    const float* xp = xemb + (size_t)b * 8192;
    for (int i = tid; i < 8192; i += 256) xe[(i >> 7) * 129 + (i & 127)] = xp[i];
    __syncthreads();

    const float isc = 0.08838834764831845f; // 1/sqrt(128)
    for (int i = tid; i < 4096; i += 256) {
        const int s = i >> 6, t = i & 63;
        const float* xs = xe + s * 129;
        const float* xt = xe + t * 129;
        float a0 = 0.f, a1 = 0.f, a2 = 0.f, a3 = 0.f;
#pragma unroll
        for (int d = 0; d < 128; d += 4) {
            a0 += xs[d]     * xt[d];
            a1 += xs[d + 1] * xt[d + 1];
            a2 += xs[d + 2] * xt[d + 2];
            a3 += xs[d + 3] * xt[d + 3];
        }
        A[s * 65 + t] = ((a0 + a1) + (a2 + a3)) * isc;
    }
    __syncthreads();
    if (tid < 64) {
        float* r = A + tid * 65;
        float m = r[0];
        for (int t = 1; t < 64; ++t) m = fmaxf(m, r[t]);
        float sum = 0.f;
        for (int t = 0; t < 64; ++t) { const float e = __expf(r[t] - m); r[t] = e; sum += e; }
        const float inv = 1.f / sum;
        for (int t = 0; t < 64; ++t) r[t] *= inv;
    }
    __syncthreads();
    const float f = attf[0] * (1.f / 16.f);
    const float* as = att_sum + (size_t)bh * 4096;
    for (int i = tid; i < 4096; i += 256)
        A[(i >> 6) * 65 + (i & 63)] += f * as[i];
    __syncthreads();

    float* op = res_si + (size_t)bh * 8192;
    for (int i = tid; i < 8192; i += 256) {
        const int s = i >> 7, d = i & 127;
        const float* ar = A + s * 65;
        float a0 = 0.f, a1 = 0.f;
#pragma unroll
        for (int t = 0; t < 64; t += 2) {
            a0 += ar[t]     * xe[t * 129 + d];
            a1 += ar[t + 1] * xe[(t + 1) * 129 + d];
        }
        op[i] = a0 + a1;
    }
}

// ---------------------------------------------------------------------------
// Kernel 3b (VALIDATED in R8; Xr-free ffn): per b. X1 = cat_h(res_si)@W_SI
// (K=512); FFN+LN -> x. shC [64][512] bf16 (swz512); after one barrier
// re-split into shA[64][128] + shH[64][128] (both swz128).
// ---------------------------------------------------------------------------
__global__ __launch_bounds__(256, 2) void k_si_ffn(
    const float* __restrict__ res_si,
    const short* __restrict__ WSIT,            // [128][512] bf16
    const short* __restrict__ W1T, const short* __restrict__ W2T,
    const float* __restrict__ g, const float* __restrict__ bb,
    float* __restrict__ out_x)
{
    const int b = blockIdx.x, tid = threadIdx.x;
    const int w = tid >> 6, lane = tid & 63, quad = lane >> 4, l16 = lane & 15;
    const int m0 = w * 16;
    __shared__ short shC[64 * 512];            // 64 KB
    short* shA = shC;                          // [64][128] after barrier
    short* shH = shC + 64 * 128;               // [64][128] after barrier

    // stage own 16 rows of cat_h(res_si) as bf16: row s, k = h*128+d (swz512)
    const float* rs = res_si + (size_t)b * 4 * 8192;
    for (int i = lane; i < 8192; i += 64) {
        const int row = m0 + (i >> 9), k = i & 511;
        const int h = k >> 7, d = k & 127;
        shC[swz(row, k, 512)] = F2BS(rs[((size_t)h * 64 + row) * 128 + d]);
    }

    // X1 = cat @ W_SI  (M=64,K=512,N=128), no residual/LN
    floatx4 acc1[8];
#pragma unroll
    for (int nt = 0; nt < 8; ++nt) acc1[nt] = (floatx4){0.f, 0.f, 0.f, 0.f};
    for (int kt = 0; kt < 16; ++kt) {
        bf16x8 a = *(const bf16x8*)&shC[swz(m0 + l16, kt * 32 + quad * 8, 512)];
#pragma unroll
        for (int nt = 0; nt < 8; ++nt) {
            bf16x8 bf = *(const bf16x8*)&WSIT[(size_t)(nt * 16 + l16) * 512 + kt * 32 + quad * 8];
            acc1[nt] = MFMA16(a, bf, acc1[nt]);
        }
    }

    __syncthreads();   // all step-A reads of shC done before overlay writes

#pragma unroll
    for (int nt = 0; nt < 8; ++nt)
#pragma unroll
        for (int r = 0; r < 4; ++r)
            shA[swz(m0 + quad * 4 + r, nt * 16 + l16, 128)] = F2BS(acc1[nt][r]);

    ffn_mfma(shA, shH, acc1, W1T, W2T, g, bb, out_x + (size_t)b * 8192, m0, lane);
}

// ---------------------------------------------------------------------------
extern "C" void kernel_launch(void* const* d_in, const int* in_sizes, int n_in,
                              void* d_out, int out_size, void* d_ws, size_t ws_size,
                              hipStream_t stream) {
    const float* x_emb = (const float*)d_in[0];
    const float* nbr   = (const float*)d_in[1];
    const int*   mask  = (const int*)d_in[2];
    const float* attf  = (const float*)d_in[3];
    const float* Wq    = (const float*)d_in[4];
    const float* Wk    = (const float*)d_in[5];
    const float* Wv    = (const float*)d_in[6];
    const float* Wfc   = (const float*)d_in[7];
    const float* g_mha = (const float*)d_in[8];
    const float* b_mha = (const float*)d_in[9];
    const float* WSI   = (const float*)d_in[10];
    const float* W1s   = (const float*)d_in[11];
    const float* W2s   = (const float*)d_in[12];
    const float* gs    = (const float*)d_in[13];
    const float* bs    = (const float*)d_in[14];
    const float* W1i   = (const float*)d_in[15];
    const float* W2i   = (const float*)d_in[16];
    const float* gi    = (const float*)d_in[17];
    const float* bi    = (const float*)d_in[18];

    // workspace (~27 MB):
    //   [0, 8M)            att_sum fp32 (zeroed each call)
    //   [8M+256, ~24.8M)   res_si fp32 (128*4*64*128)
    //   [25M, +96K)        bf16 W^T for QKV
    //   [26M, +656K)       bf16 transposed weights (FFN/SI)
    float* att_sum = (float*)d_ws;
    float* res_si = (float*)((char*)d_ws + (size_t)8 * 1024 * 1024 + 256);
    short* wqkv = (short*)((char*)d_ws + (size_t)25 * 1024 * 1024);
    short* WqT  = wqkv;                // 16384
    short* WkT  = WqT + 16384;
    short* WvT  = WkT + 16384;
    short* wb   = (short*)((char*)d_ws + (size_t)26 * 1024 * 1024);
    short* WfcT = wb;                  // 16384
    short* W1iT = WfcT + 16384;        // 65536
    short* W2iT = W1iT + 65536;
    short* WSIT = W2iT + 65536;
    short* W1sT = WSIT + 65536;
    short* W2sT = W1sT + 65536;

    float* out_x  = (float*)d_out;                       // output 0: x
    float* out_nb = out_x + (size_t)NA * SS * DD;        // output 1: nb
    float* res_ws = out_nb;   // res staged in out_nb storage (element-exact)

    hipMemsetAsync(d_ws, 0, (size_t)NA * HH * SS * SS * sizeof(float), stream);

    k_prep<<<256, 256, 0, stream>>>(Wq, Wk, Wv, Wfc, W1i, W2i, WSI, W1s, W2s,
                                    WqT, WkT, WvT,
                                    WfcT, W1iT, W2iT, WSIT, W1sT, W2sT);
    k_attn<<<NA * NN_, 256, 0, stream>>>(nbr, mask, WqT, WkT, WvT,
                                         att_sum, res_ws);
    k_mha_ffn<<<NA * NN_ / 2, 256, 0, stream>>>(nbr, res_ws, WfcT, g_mha, b_mha,
                                                W1iT, W2iT, gi, bi, out_nb);
    k_self<<<NA * HH, 256, 0, stream>>>(x_emb, att_sum, attf, res_si);
    k_si_ffn<<<NA, 256, 0, stream>>>(res_si, WSIT, W1sT, W2sT, gs, bs, out_x);
}

// Round 10
// 601.381 us; speedup vs baseline: 1.2847x; 1.0440x over previous
//
#include <hip/hip_runtime.h>
#include <hip/hip_bf16.h>

// Problem dims (fixed)
#define NA   128   // agents
#define NN_  16    // neighbors
#define SS   64    // timesteps
#define DD   128   // model dim
#define HH   4     // heads

typedef __attribute__((ext_vector_type(8))) short bf16x8;   // 8 bf16 = 4 VGPRs
typedef __attribute__((ext_vector_type(4))) float floatx4;  // MFMA C/D
typedef __attribute__((ext_vector_type(4))) short shortx4;  // 4 bf16 = 8B

#define MFMA16(a, b, c) __builtin_amdgcn_mfma_f32_16x16x32_bf16((a), (b), (c), 0, 0, 0)

__device__ __forceinline__ short F2BS(float f) {
    __hip_bfloat16 h = __float2bfloat16(f);
    short s;
    __builtin_memcpy(&s, &h, 2);
    return s;
}

__device__ __forceinline__ float BS2F(short s) {
    unsigned u = ((unsigned)(unsigned short)s) << 16;
    float f;
    __builtin_memcpy(&f, &u, 4);
    return f;
}

// XOR-swizzle for bf16 LDS tiles whose row stride is a multiple of 128B:
// flips byte bits 4..6 by (row&7) -> spreads the 16B slots of a column
// across 8 bank groups. Preserves 8B/16B alignment (bits 0..3 untouched).
// MUST be applied on both write and read sides (ld = row stride in shorts).
__device__ __forceinline__ int swz(int row, int col, int ld) {
    const int byte = ((row * ld + col) << 1) ^ ((row & 7) << 4);
    return byte >> 1;
}

// ---------------------------------------------------------------------------
// Weight prep: bf16 + transpose so MFMA B-fragments (B[k][n], lane n=lane&15,
// k=quad*8+j) are 16B-contiguous reads: store W^T[n][k] row-major.
//   WqT/WkT/WvT/WfcT [128][128], W1iT/W1sT [512][128], W2iT/W2sT/WSIT [128][512]
// ---------------------------------------------------------------------------
__global__ __launch_bounds__(256) void k_prep(
    const float* __restrict__ Wq, const float* __restrict__ Wk,
    const float* __restrict__ Wv,
    const float* __restrict__ Wfc, const float* __restrict__ W1i,
    const float* __restrict__ W2i, const float* __restrict__ WSI,
    const float* __restrict__ W1s, const float* __restrict__ W2s,
    short* __restrict__ WqT, short* __restrict__ WkT, short* __restrict__ WvT,
    short* __restrict__ WfcT, short* __restrict__ W1iT, short* __restrict__ W2iT,
    short* __restrict__ WSIT, short* __restrict__ W1sT, short* __restrict__ W2sT)
{
    const int i = blockIdx.x * 256 + threadIdx.x;   // [0, 65536)
    if (i < 128 * 128) {
        const int n = i >> 7, k = i & 127;
        const int src = k * 128 + n;
        WqT[i]  = F2BS(Wq[src]);
        WkT[i]  = F2BS(Wk[src]);
        WvT[i]  = F2BS(Wv[src]);
        WfcT[i] = F2BS(Wfc[src]);
    }
    {   // [512][128] from (128,512)
        const int n = i >> 7, k = i & 127;
        W1iT[i] = F2BS(W1i[k * 512 + n]);
        W1sT[i] = F2BS(W1s[k * 512 + n]);
    }
    {   // [128][512] from (512,128)
        const int n = i >> 9, f = i & 511;
        W2iT[i] = F2BS(W2i[f * 128 + n]);
        W2sT[i] = F2BS(W2s[f * 128 + n]);
        WSIT[i] = F2BS(WSI[f * 128 + n]);
    }
}

// ---------------------------------------------------------------------------
// Kernel 1 (R13): per bn, heads fused. QKV MFMA, masked wave-parallel
// softmax, PV MFMA -> res_ws. P handling: if P_ws != null, write P as plain
// bf16 stores (NO device-scope atomics -> no cross-XCD RMW serialization;
// k_self sums the 16 neighbors); else legacy atomicAdd into att_sum.
// ---------------------------------------------------------------------------
__global__ __launch_bounds__(256) void k_attn(
    const float* __restrict__ nbr,            // (2048,64,128) fp32
    const int* __restrict__ mask,             // (2048,64,64) int32 0/1
    const short* __restrict__ WqT,            // [128][128] bf16 (W^T)
    const short* __restrict__ WkT,
    const short* __restrict__ WvT,
    float* __restrict__ att_sum,              // (128,4,64,64) fp32 (fallback)
    short* __restrict__ P_ws,                 // (2048,4,64,64) bf16 or null
    float* __restrict__ res_ws)               // (2048,64,128) fp32
{
    const int bn  = blockIdx.x;
    const int b   = bn >> 4;
    const int tid = threadIdx.x;
    const int lane = tid & 63, quad = lane >> 4, l16 = lane & 15;
    const int m0 = (tid >> 6) * 16;           // wave-private 16 rows

    __shared__ short shE[64 * 128];           // 16 KB; reused as shP after QKV
    __shared__ short shQ[64 * 128];           // 16 KB
    __shared__ short shK[64 * 128];           // 16 KB
    __shared__ short shVT[128 * 64];          // 16 KB, V^T[d][t]
    short* const shP = shE;                   // [64][64] P (wave-private rows)

    // ---- stage E -> bf16 (swizzled), float4 loads ----
    const float* E = nbr + (size_t)bn * 8192;
    for (int i = tid; i < 2048; i += 256) {
        const floatx4 v = *(const floatx4*)&E[i * 4];
        const int row = i >> 5, col = (i & 31) * 4;
        shortx4 o;
#pragma unroll
        for (int j = 0; j < 4; ++j) o[j] = F2BS(v[j]);
        *(shortx4*)&shE[swz(row, col, 128)] = o;
    }

    // mask into regs once, reused by all 4 heads (C-fragment positions)
    const int* mrow = mask + (size_t)bn * 4096;
    int mv[4][4];
#pragma unroll
    for (int nt = 0; nt < 4; ++nt)
#pragma unroll
        for (int r = 0; r < 4; ++r)
            mv[nt][r] = mrow[(m0 + quad * 4 + r) * 64 + nt * 16 + l16];

    __syncthreads();

    // ---- QKV: (64x128)@(128x128) x3, fused over nt ----
    bf16x8 ax[4];
#pragma unroll
    for (int kt = 0; kt < 4; ++kt)
        ax[kt] = *(const bf16x8*)&shE[swz(m0 + l16, kt * 32 + quad * 8, 128)];

#pragma unroll
    for (int nt = 0; nt < 8; ++nt) {
        floatx4 aq = {0.f, 0.f, 0.f, 0.f};
        floatx4 ak = {0.f, 0.f, 0.f, 0.f};
        floatx4 av = {0.f, 0.f, 0.f, 0.f};
#pragma unroll
        for (int kt = 0; kt < 4; ++kt) {
            const size_t wo = (size_t)(nt * 16 + l16) * 128 + kt * 32 + quad * 8;
            aq = MFMA16(ax[kt], *(const bf16x8*)&WqT[wo], aq);
            ak = MFMA16(ax[kt], *(const bf16x8*)&WkT[wo], ak);
            av = MFMA16(ax[kt], *(const bf16x8*)&WvT[wo], av);
        }
        shortx4 ov;
#pragma unroll
        for (int r = 0; r < 4; ++r) {
            const int row = m0 + quad * 4 + r, col = nt * 16 + l16;
            shQ[swz(row, col, 128)] = F2BS(aq[r]);
            shK[swz(row, col, 128)] = F2BS(ak[r]);
            ov[r] = F2BS(av[r]);
        }
        // V stored transposed: VT[d][t], 4 consecutive t per lane -> b64 write
        *(shortx4*)&shVT[swz(nt * 16 + l16, m0 + quad * 4, 64)] = ov;
    }
    __syncthreads();   // shE dead; shQ/shK/shVT visible to all waves

    const float iscale = 0.17677669529663687f; // 1/sqrt(32)
    float* const out = res_ws + (size_t)bn * 8192;

    for (int h = 0; h < 4; ++h) {
        // ---- scores: S = Q_h(64x32) @ K_h^T(32x64) ----
        const bf16x8 qa = *(const bf16x8*)&shQ[swz(m0 + l16, h * 32 + quad * 8, 128)];
        floatx4 sa[4];
#pragma unroll
        for (int nt = 0; nt < 4; ++nt) {
            const bf16x8 kb = *(const bf16x8*)&shK[swz(nt * 16 + l16, h * 32 + quad * 8, 128)];
            const floatx4 z = {0.f, 0.f, 0.f, 0.f};
            sa[nt] = MFMA16(qa, kb, z);
        }
        // ---- masked softmax, wave-parallel (row = 4 nt frags x 16 lanes) ----
        float p[4][4];
#pragma unroll
        for (int r = 0; r < 4; ++r) {
            float m = -1e30f;
#pragma unroll
            for (int nt = 0; nt < 4; ++nt) {
                p[nt][r] = mv[nt][r] ? sa[nt][r] * iscale : -1e9f;
                m = fmaxf(m, p[nt][r]);
            }
            m = fmaxf(m, __shfl_xor(m, 1, 64));
            m = fmaxf(m, __shfl_xor(m, 2, 64));
            m = fmaxf(m, __shfl_xor(m, 4, 64));
            m = fmaxf(m, __shfl_xor(m, 8, 64));
            float sum = 0.f;
#pragma unroll
            for (int nt = 0; nt < 4; ++nt) {
                const float e = __expf(p[nt][r] - m);
                p[nt][r] = e; sum += e;
            }
            sum += __shfl_xor(sum, 1, 64);
            sum += __shfl_xor(sum, 2, 64);
            sum += __shfl_xor(sum, 4, 64);
            sum += __shfl_xor(sum, 8, 64);
            const float inv = 1.f / sum;
#pragma unroll
            for (int nt = 0; nt < 4; ++nt) p[nt][r] *= inv;
        }
        // ---- P out (bf16 stores or legacy atomics) + P -> LDS (own rows) ----
        if (P_ws) {
            short* const pp = P_ws + ((size_t)(bn * 4 + h)) * 4096;
#pragma unroll
            for (int nt = 0; nt < 4; ++nt)
#pragma unroll
                for (int r = 0; r < 4; ++r) {
                    const int row = m0 + quad * 4 + r, col = nt * 16 + l16;
                    const short v = F2BS(p[nt][r]);
                    pp[row * 64 + col] = v;
                    shP[swz(row, col, 64)] = v;
                }
        } else {
            float* const as = att_sum + ((size_t)(b * 4 + h)) * 4096;
#pragma unroll
            for (int nt = 0; nt < 4; ++nt)
#pragma unroll
                for (int r = 0; r < 4; ++r) {
                    const int row = m0 + quad * 4 + r, col = nt * 16 + l16;
                    atomicAdd(as + row * 64 + col, p[nt][r]);
                    shP[swz(row, col, 64)] = F2BS(p[nt][r]);
                }
        }
        // ---- PV: (64x64)@(64x32) ----
        const bf16x8 pa0 = *(const bf16x8*)&shP[swz(m0 + l16, quad * 8, 64)];
        const bf16x8 pa1 = *(const bf16x8*)&shP[swz(m0 + l16, 32 + quad * 8, 64)];
#pragma unroll
        for (int nt = 0; nt < 2; ++nt) {
            floatx4 acc = {0.f, 0.f, 0.f, 0.f};
            acc = MFMA16(pa0, *(const bf16x8*)&shVT[swz(h * 32 + nt * 16 + l16, quad * 8, 64)], acc);
            acc = MFMA16(pa1, *(const bf16x8*)&shVT[swz(h * 32 + nt * 16 + l16, 32 + quad * 8, 64)], acc);
#pragma unroll
            for (int r = 0; r < 4; ++r)
                out[(m0 + quad * 4 + r) * 128 + h * 32 + nt * 16 + l16] = acc[r];
        }
    }
}

// ---------------------------------------------------------------------------
// MFMA FFN + LN (single-tile helper, used by k_si_ffn; VALIDATED R8/R11).
// On entry accO holds X (post-LN residual) and shA holds bf16 X.
// DFF in 4 chunks of 128 -> shH [64][128] = 16 KB.
// ---------------------------------------------------------------------------
__device__ __forceinline__ void ffn_mfma(
    const short* shA, short* shH, floatx4 (&accO)[8],
    const short* __restrict__ W1T,   // [512][128] bf16
    const short* __restrict__ W2T,   // [128][512] bf16
    const float* __restrict__ g, const float* __restrict__ bb,
    float* outp, int m0, int lane)
{
    const int quad = lane >> 4, l16 = lane & 15;

    bf16x8 ax[4];
#pragma unroll
    for (int kt = 0; kt < 4; ++kt)
        ax[kt] = *(const bf16x8*)&shA[swz(m0 + l16, kt * 32 + quad * 8, 128)];

#pragma unroll
    for (int fc = 0; fc < 4; ++fc) {
#pragma unroll
        for (int nt = 0; nt < 8; ++nt) {
            floatx4 acc = {0.f, 0.f, 0.f, 0.f};
            const int n0 = fc * 128 + nt * 16;
#pragma unroll
            for (int kt = 0; kt < 4; ++kt) {
                bf16x8 bf = *(const bf16x8*)&W1T[(size_t)(n0 + l16) * 128 + kt * 32 + quad * 8];
                acc = MFMA16(ax[kt], bf, acc);
            }
#pragma unroll
            for (int r = 0; r < 4; ++r)
                shH[swz(m0 + quad * 4 + r, nt * 16 + l16, 128)] = F2BS(fmaxf(acc[r], 0.f));
        }
        bf16x8 ah[4];
#pragma unroll
        for (int kt = 0; kt < 4; ++kt)
            ah[kt] = *(const bf16x8*)&shH[swz(m0 + l16, kt * 32 + quad * 8, 128)];
#pragma unroll
        for (int nt = 0; nt < 8; ++nt)
#pragma unroll
            for (int kt = 0; kt < 4; ++kt) {
                bf16x8 bf = *(const bf16x8*)&W2T[(size_t)(nt * 16 + l16) * 512 + fc * 128 + kt * 32 + quad * 8];
                accO[nt] = MFMA16(ah[kt], bf, accO[nt]);
            }
    }

    float mean[4], rstd[4];
#pragma unroll
    for (int r = 0; r < 4; ++r) {
        float p = 0.f;
#pragma unroll
        for (int nt = 0; nt < 8; ++nt) p += accO[nt][r];
        p += __shfl_xor(p, 1, 64); p += __shfl_xor(p, 2, 64);
        p += __shfl_xor(p, 4, 64); p += __shfl_xor(p, 8, 64);
        mean[r] = p * (1.f / 128.f);
        float q = 0.f;
#pragma unroll
        for (int nt = 0; nt < 8; ++nt) { const float d = accO[nt][r] - mean[r]; q += d * d; }
        q += __shfl_xor(q, 1, 64); q += __shfl_xor(q, 2, 64);
        q += __shfl_xor(q, 4, 64); q += __shfl_xor(q, 8, 64);
        rstd[r] = rsqrtf(q * (1.f / 128.f) + 1e-5f);
    }
#pragma unroll
    for (int nt = 0; nt < 8; ++nt) {
        const int colc = nt * 16 + l16;
        const float gc = g[colc], bc = bb[colc];
#pragma unroll
        for (int r = 0; r < 4; ++r) {
            const int row = m0 + quad * 4 + r;
            outp[row * 128 + colc] = (accO[nt][r] - mean[r]) * rstd[r] * gc + bc;
        }
    }
}

// in-place LN over C-fragment regs + bf16 store to swizzled LDS (own rows)
__device__ __forceinline__ void ln_inplace(
    floatx4 (&acc)[8], const float* __restrict__ g, const float* __restrict__ bb,
    short* shX, int m0, int quad, int l16)
{
    float mean[4], rstd[4];
#pragma unroll
    for (int r = 0; r < 4; ++r) {
        float p = 0.f;
#pragma unroll
        for (int nt = 0; nt < 8; ++nt) p += acc[nt][r];
        p += __shfl_xor(p, 1, 64); p += __shfl_xor(p, 2, 64);
        p += __shfl_xor(p, 4, 64); p += __shfl_xor(p, 8, 64);
        mean[r] = p * (1.f / 128.f);
        float q = 0.f;
#pragma unroll
        for (int nt = 0; nt < 8; ++nt) { const float d = acc[nt][r] - mean[r]; q += d * d; }
        q += __shfl_xor(q, 1, 64); q += __shfl_xor(q, 2, 64);
        q += __shfl_xor(q, 4, 64); q += __shfl_xor(q, 8, 64);
        rstd[r] = rsqrtf(q * (1.f / 128.f) + 1e-5f);
    }
#pragma unroll
    for (int nt = 0; nt < 8; ++nt) {
        const int colc = nt * 16 + l16;
        const float gc = g[colc], bc = bb[colc];
#pragma unroll
        for (int r = 0; r < 4; ++r) {
            acc[nt][r] = (acc[nt][r] - mean[r]) * rstd[r] * gc + bc;
            shX[swz(m0 + quad * 4 + r, colc, 128)] = F2BS(acc[nt][r]);
        }
    }
}

// ---------------------------------------------------------------------------
// Kernel 2 (R12, VALIDATED): TWO bn tiles per block (grid 1024). Every weight
// B-fragment is loaded ONCE and feeds TWO independent MFMAs.
// ---------------------------------------------------------------------------
__global__ __launch_bounds__(256, 2) void k_mha_ffn(
    const float* __restrict__ nbr,
    const float* res_in,                      // aliases out_nb
    const short* __restrict__ WfcT,           // [128][128] bf16
    const float* __restrict__ g1, const float* __restrict__ b1,
    const short* __restrict__ W1T, const short* __restrict__ W2T,
    const float* __restrict__ g2, const float* __restrict__ b2,
    float* out_nb)
{
    const int bn0 = blockIdx.x * 2;
    const int tid = threadIdx.x;
    const int lane = tid & 63, quad = lane >> 4, l16 = lane & 15;
    const int m0 = (tid >> 6) * 16;
    __shared__ short lds0[64 * 128];   // tile0: res -> X -> H chunks (16 KB)
    __shared__ short lds1[64 * 128];   // tile1: same (16 KB)

    // ---- stage both res tiles (own rows, swizzled, float4 loads) ----
    const float* rp0 = res_in + (size_t)bn0 * 8192;
    const float* rp1 = res_in + (size_t)(bn0 + 1) * 8192;
    for (int j = lane; j < 512; j += 64) {
        const int row = m0 + (j >> 5), col = (j & 31) * 4;
        const floatx4 v0 = *(const floatx4*)&rp0[row * 128 + col];
        const floatx4 v1 = *(const floatx4*)&rp1[row * 128 + col];
        shortx4 o0, o1;
#pragma unroll
        for (int t = 0; t < 4; ++t) { o0[t] = F2BS(v0[t]); o1[t] = F2BS(v1[t]); }
        *(shortx4*)&lds0[swz(row, col, 128)] = o0;
        *(shortx4*)&lds1[swz(row, col, 128)] = o1;
    }

    bf16x8 ax0[4], ax1[4];
#pragma unroll
    for (int kt = 0; kt < 4; ++kt) {
        ax0[kt] = *(const bf16x8*)&lds0[swz(m0 + l16, kt * 32 + quad * 8, 128)];
        ax1[kt] = *(const bf16x8*)&lds1[swz(m0 + l16, kt * 32 + quad * 8, 128)];
    }

    // ---- O = res @ Wfc + E, both tiles, shared weight fragments ----
    floatx4 acc0[8], acc1[8];
    const float* E0 = nbr + (size_t)bn0 * 8192;
    const float* E1 = nbr + (size_t)(bn0 + 1) * 8192;
#pragma unroll
    for (int nt = 0; nt < 8; ++nt)
#pragma unroll
        for (int r = 0; r < 4; ++r) {
            const int idx = (m0 + quad * 4 + r) * 128 + nt * 16 + l16;
            acc0[nt][r] = E0[idx];
            acc1[nt][r] = E1[idx];
        }
#pragma unroll
    for (int nt = 0; nt < 8; ++nt)
#pragma unroll
        for (int kt = 0; kt < 4; ++kt) {
            bf16x8 bf = *(const bf16x8*)&WfcT[(size_t)(nt * 16 + l16) * 128 + kt * 32 + quad * 8];
            acc0[nt] = MFMA16(ax0[kt], bf, acc0[nt]);
            acc1[nt] = MFMA16(ax1[kt], bf, acc1[nt]);
        }

    // ---- LN in place -> acc = X; bf16 X into lds (own rows) ----
    ln_inplace(acc0, g1, b1, lds0, m0, quad, l16);
    ln_inplace(acc1, g1, b1, lds1, m0, quad, l16);

    // reload A fragments = X
#pragma unroll
    for (int kt = 0; kt < 4; ++kt) {
        ax0[kt] = *(const bf16x8*)&lds0[swz(m0 + l16, kt * 32 + quad * 8, 128)];
        ax1[kt] = *(const bf16x8*)&lds1[swz(m0 + l16, kt * 32 + quad * 8, 128)];
    }

    // ---- FFN: DFF in 4 chunks; H overlays lds (X already in ax regs) ----
#pragma unroll
    for (int fc = 0; fc < 4; ++fc) {
#pragma unroll
        for (int nt = 0; nt < 8; ++nt) {
            floatx4 h0 = {0.f, 0.f, 0.f, 0.f};
            floatx4 h1 = {0.f, 0.f, 0.f, 0.f};
            const int n0 = fc * 128 + nt * 16;
#pragma unroll
            for (int kt = 0; kt < 4; ++kt) {
                bf16x8 bf = *(const bf16x8*)&W1T[(size_t)(n0 + l16) * 128 + kt * 32 + quad * 8];
                h0 = MFMA16(ax0[kt], bf, h0);
                h1 = MFMA16(ax1[kt], bf, h1);
            }
#pragma unroll
            for (int r = 0; r < 4; ++r) {
                const int o = swz(m0 + quad * 4 + r, nt * 16 + l16, 128);
                lds0[o] = F2BS(fmaxf(h0[r], 0.f));
                lds1[o] = F2BS(fmaxf(h1[r], 0.f));
            }
        }
        bf16x8 ah0[4], ah1[4];
#pragma unroll
        for (int kt = 0; kt < 4; ++kt) {
            ah0[kt] = *(const bf16x8*)&lds0[swz(m0 + l16, kt * 32 + quad * 8, 128)];
            ah1[kt] = *(const bf16x8*)&lds1[swz(m0 + l16, kt * 32 + quad * 8, 128)];
        }
#pragma unroll
        for (int nt = 0; nt < 8; ++nt)
#pragma unroll
            for (int kt = 0; kt < 4; ++kt) {
                bf16x8 bf = *(const bf16x8*)&W2T[(size_t)(nt * 16 + l16) * 512 + fc * 128 + kt * 32 + quad * 8];
                acc0[nt] = MFMA16(ah0[kt], bf, acc0[nt]);
                acc1[nt] = MFMA16(ah1[kt], bf, acc1[nt]);
            }
    }

    // ---- final LN + store (write direct to global) ----
    float* const op0 = out_nb + (size_t)bn0 * 8192;
    float* const op1 = out_nb + (size_t)(bn0 + 1) * 8192;
    {
        float mean[4], rstd[4];
#pragma unroll
        for (int r = 0; r < 4; ++r) {
            float p = 0.f;
#pragma unroll
            for (int nt = 0; nt < 8; ++nt) p += acc0[nt][r];
            p += __shfl_xor(p, 1, 64); p += __shfl_xor(p, 2, 64);
            p += __shfl_xor(p, 4, 64); p += __shfl_xor(p, 8, 64);
            mean[r] = p * (1.f / 128.f);
            float q = 0.f;
#pragma unroll
            for (int nt = 0; nt < 8; ++nt) { const float d = acc0[nt][r] - mean[r]; q += d * d; }
            q += __shfl_xor(q, 1, 64); q += __shfl_xor(q, 2, 64);
            q += __shfl_xor(q, 4, 64); q += __shfl_xor(q, 8, 64);
            rstd[r] = rsqrtf(q * (1.f / 128.f) + 1e-5f);
        }
#pragma unroll
        for (int nt = 0; nt < 8; ++nt) {
            const int colc = nt * 16 + l16;
            const float gc = g2[colc], bc = b2[colc];
#pragma unroll
            for (int r = 0; r < 4; ++r)
                op0[(m0 + quad * 4 + r) * 128 + colc] = (acc0[nt][r] - mean[r]) * rstd[r] * gc + bc;
        }
    }
    {
        float mean[4], rstd[4];
#pragma unroll
        for (int r = 0; r < 4; ++r) {
            float p = 0.f;
#pragma unroll
            for (int nt = 0; nt < 8; ++nt) p += acc1[nt][r];
            p += __shfl_xor(p, 1, 64); p += __shfl_xor(p, 2, 64);
            p += __shfl_xor(p, 4, 64); p += __shfl_xor(p, 8, 64);
            mean[r] = p * (1.f / 128.f);
            float q = 0.f;
#pragma unroll
            for (int nt = 0; nt < 8; ++nt) { const float d = acc1[nt][r] - mean[r]; q += d * d; }
            q += __shfl_xor(q, 1, 64); q += __shfl_xor(q, 2, 64);
            q += __shfl_xor(q, 4, 64); q += __shfl_xor(q, 8, 64);
            rstd[r] = rsqrtf(q * (1.f / 128.f) + 1e-5f);
        }
#pragma unroll
        for (int nt = 0; nt < 8; ++nt) {
            const int colc = nt * 16 + l16;
            const float gc = g2[colc], bc = b2[colc];
#pragma unroll
            for (int r = 0; r < 4; ++r)
                op1[(m0 + quad * 4 + r) * 128 + colc] = (acc1[nt][r] - mean[r]) * rstd[r] * gc + bc;
        }
    }
}

// ---------------------------------------------------------------------------
// Kernel 3a (R13): self-softmax + att_factor/16 * (sum of P over neighbors);
// @ x_emb. If P_ws != null sums 16 bf16 P tiles, else reads legacy att_sum.
// ---------------------------------------------------------------------------
__global__ __launch_bounds__(256) void k_self(
    const float* __restrict__ xemb,            // (128,64,128) fp32
    const float* __restrict__ att_sum,         // (128,4,64,64) (fallback)
    const short* __restrict__ P_ws,            // (2048,4,64,64) bf16 or null
    const float* __restrict__ attf,            // scalar fp32
    float* __restrict__ res_si)                // (128,4,64,128) fp32
{
    const int bh = blockIdx.x;   // b*4 + h
    const int b = bh >> 2;
    const int h = bh & 3;
    const int tid = threadIdx.x;
    __shared__ float xe[64 * 129];
    __shared__ float A[64 * 65];

    const float* xp = xemb + (size_t)b * 8192;
    for (int i = tid; i < 8192; i += 256) xe[(i >> 7) * 129 + (i & 127)] = xp[i];
    __syncthreads();

    const float isc = 0.08838834764831845f; // 1/sqrt(128)
    for (int i = tid; i < 4096; i += 256) {
        const int s = i >> 6, t = i & 63;
        const float* xs = xe + s * 129;
        const float* xt = xe + t * 129;
        float a0 = 0.f, a1 = 0.f, a2 = 0.f, a3 = 0.f;
#pragma unroll
        for (int d = 0; d < 128; d += 4) {
            a0 += xs[d]     * xt[d];
            a1 += xs[d + 1] * xt[d + 1];
            a2 += xs[d + 2] * xt[d + 2];
            a3 += xs[d + 3] * xt[d + 3];
        }
        A[s * 65 + t] = ((a0 + a1) + (a2 + a3)) * isc;
    }
    __syncthreads();
    if (tid < 64) {
        float* r = A + tid * 65;
        float m = r[0];
        for (int t = 1; t < 64; ++t) m = fmaxf(m, r[t]);
        float sum = 0.f;
        for (int t = 0; t < 64; ++t) { const float e = __expf(r[t] - m); r[t] = e; sum += e; }
        const float inv = 1.f / sum;
        for (int t = 0; t < 64; ++t) r[t] *= inv;
    }
    __syncthreads();
    const float f = attf[0] * (1.f / 16.f);
    if (P_ws) {
        // base for nn=0: ((b*16+0)*4 + h) * 4096
        const short* pb = P_ws + ((size_t)(b * 16) * 4 + h) * 4096;
        for (int i = tid; i < 4096; i += 256) {
            float s = 0.f;
#pragma unroll
            for (int nn = 0; nn < 16; ++nn)
                s += BS2F(pb[(size_t)nn * 4 * 4096 + i]);
            A[(i >> 6) * 65 + (i & 63)] += f * s;
        }
    } else {
        const float* as = att_sum + (size_t)bh * 4096;
        for (int i = tid; i < 4096; i += 256)
            A[(i >> 6) * 65 + (i & 63)] += f * as[i];
    }
    __syncthreads();

    float* op = res_si + (size_t)bh * 8192;
    for (int i = tid; i < 8192; i += 256) {
        const int s = i >> 7, d = i & 127;
        const float* ar = A + s * 65;
        float a0 = 0.f, a1 = 0.f;
#pragma unroll
        for (int t = 0; t < 64; t += 2) {
            a0 += ar[t]     * xe[t * 129 + d];
            a1 += ar[t + 1] * xe[(t + 1) * 129 + d];
        }
        op[i] = a0 + a1;
    }
}

// ---------------------------------------------------------------------------
// Kernel 3b (VALIDATED in R8; Xr-free ffn): per b. X1 = cat_h(res_si)@W_SI
// (K=512); FFN+LN -> x. shC [64][512] bf16 (swz512); after one barrier
// re-split into shA[64][128] + shH[64][128] (both swz128).
// ---------------------------------------------------------------------------
__global__ __launch_bounds__(256, 2) void k_si_ffn(
    const float* __restrict__ res_si,
    const short* __restrict__ WSIT,            // [128][512] bf16
    const short* __restrict__ W1T, const short* __restrict__ W2T,
    const float* __restrict__ g, const float* __restrict__ bb,
    float* __restrict__ out_x)
{
    const int b = blockIdx.x, tid = threadIdx.x;
    const int w = tid >> 6, lane = tid & 63, quad = lane >> 4, l16 = lane & 15;
    const int m0 = w * 16;
    __shared__ short shC[64 * 512];            // 64 KB
    short* shA = shC;                          // [64][128] after barrier
    short* shH = shC + 64 * 128;               // [64][128] after barrier

    // stage own 16 rows of cat_h(res_si) as bf16: row s, k = h*128+d (swz512)
    const float* rs = res_si + (size_t)b * 4 * 8192;
    for (int i = lane; i < 8192; i += 64) {
        const int row = m0 + (i >> 9), k = i & 511;
        const int h = k >> 7, d = k & 127;
        shC[swz(row, k, 512)] = F2BS(rs[((size_t)h * 64 + row) * 128 + d]);
    }

    // X1 = cat @ W_SI  (M=64,K=512,N=128), no residual/LN
    floatx4 acc1[8];
#pragma unroll
    for (int nt = 0; nt < 8; ++nt) acc1[nt] = (floatx4){0.f, 0.f, 0.f, 0.f};
    for (int kt = 0; kt < 16; ++kt) {
        bf16x8 a = *(const bf16x8*)&shC[swz(m0 + l16, kt * 32 + quad * 8, 512)];
#pragma unroll
        for (int nt = 0; nt < 8; ++nt) {
            bf16x8 bf = *(const bf16x8*)&WSIT[(size_t)(nt * 16 + l16) * 512 + kt * 32 + quad * 8];
            acc1[nt] = MFMA16(a, bf, acc1[nt]);
        }
    }

    __syncthreads();   // all step-A reads of shC done before overlay writes

#pragma unroll
    for (int nt = 0; nt < 8; ++nt)
#pragma unroll
        for (int r = 0; r < 4; ++r)
            shA[swz(m0 + quad * 4 + r, nt * 16 + l16, 128)] = F2BS(acc1[nt][r]);

    ffn_mfma(shA, shH, acc1, W1T, W2T, g, bb, out_x + (size_t)b * 8192, m0, lane);
}

// ---------------------------------------------------------------------------
extern "C" void kernel_launch(void* const* d_in, const int* in_sizes, int n_in,
                              void* d_out, int out_size, void* d_ws, size_t ws_size,
                              hipStream_t stream) {
    const float* x_emb = (const float*)d_in[0];
    const float* nbr   = (const float*)d_in[1];
    const int*   mask  = (const int*)d_in[2];
    const float* attf  = (const float*)d_in[3];
    const float* Wq    = (const float*)d_in[4];
    const float* Wk    = (const float*)d_in[5];
    const float* Wv    = (const float*)d_in[6];
    const float* Wfc   = (const float*)d_in[7];
    const float* g_mha = (const float*)d_in[8];
    const float* b_mha = (const float*)d_in[9];
    const float* WSI   = (const float*)d_in[10];
    const float* W1s   = (const float*)d_in[11];
    const float* W2s   = (const float*)d_in[12];
    const float* gs    = (const float*)d_in[13];
    const float* bs    = (const float*)d_in[14];
    const float* W1i   = (const float*)d_in[15];
    const float* W2i   = (const float*)d_in[16];
    const float* gi    = (const float*)d_in[17];
    const float* bi    = (const float*)d_in[18];

    // workspace:
    //   [0, 8.4M)          att_sum fp32 (fallback only; zeroed if used)
    //   [8.5M, ~25.3M)     res_si fp32 (128*4*64*128)
    //   [25.5M, +96K)      bf16 W^T for QKV
    //   [26M, +656K)       bf16 transposed weights (FFN/SI)
    //   [27M, +67.1M)      P_ws bf16 (2048,4,64,64) if ws_size permits
    float* att_sum = (float*)d_ws;
    float* res_si = (float*)((char*)d_ws + (size_t)8 * 1024 * 1024 + 512 * 1024);
    short* wqkv = (short*)((char*)d_ws + (size_t)25 * 1024 * 1024 + 512 * 1024);
    short* WqT  = wqkv;                // 16384
    short* WkT  = WqT + 16384;
    short* WvT  = WkT + 16384;
    short* wb   = (short*)((char*)d_ws + (size_t)26 * 1024 * 1024);
    short* WfcT = wb;                  // 16384
    short* W1iT = WfcT + 16384;        // 65536
    short* W2iT = W1iT + 65536;
    short* WSIT = W2iT + 65536;
    short* W1sT = WSIT + 65536;
    short* W2sT = W1sT + 65536;

    const size_t pws_off  = (size_t)27 * 1024 * 1024;
    const size_t pws_size = (size_t)NA * NN_ * HH * SS * SS * sizeof(short); // 67.1 MB
    short* P_ws = nullptr;
    if (ws_size >= pws_off + pws_size)
        P_ws = (short*)((char*)d_ws + pws_off);

    float* out_x  = (float*)d_out;                       // output 0: x
    float* out_nb = out_x + (size_t)NA * SS * DD;        // output 1: nb
    float* res_ws = out_nb;   // res staged in out_nb storage (element-exact)

    if (!P_ws)
        hipMemsetAsync(d_ws, 0, (size_t)NA * HH * SS * SS * sizeof(float), stream);

    k_prep<<<256, 256, 0, stream>>>(Wq, Wk, Wv, Wfc, W1i, W2i, WSI, W1s, W2s,
                                    WqT, WkT, WvT,
                                    WfcT, W1iT, W2iT, WSIT, W1sT, W2sT);
    k_attn<<<NA * NN_, 256, 0, stream>>>(nbr, mask, WqT, WkT, WvT,
                                         att_sum, P_ws, res_ws);
    k_mha_ffn<<<NA * NN_ / 2, 256, 0, stream>>>(nbr, res_ws, WfcT, g_mha, b_mha,
                                                W1iT, W2iT, gi, bi, out_nb);
    k_self<<<NA * HH, 256, 0, stream>>>(x_emb, att_sum, P_ws, attf, res_si);
    k_si_ffn<<<NA, 256, 0, stream>>>(res_si, WSIT, W1sT, W2sT, gs, bs, out_x);
}